// Round 10
// baseline (177.231 us; speedup 1.0000x reference)
//
#include <hip/hip_runtime.h>

// TreeDecoderTeacherForced — R9: R6 structure (LDS-staged A+W, XOR swizzle,
// __syncthreads barriers, depth-2 A prefetch, fused child idx, bf16 feat;
// NT stores REVERTED — they inflate HBM writes ~2x via partial-line RMW;
// raw barriers REVERTED — regressed in R8) with a 128-row x 512-thread tile:
// 8 waves/block, 48KB LDS -> 3 blocks/CU = 24 waves/CU (2x prior 12) to
// double outstanding gather misses (latency-bound gather floor scales with
// resident waves).

using short8 = __attribute__((ext_vector_type(8))) short;
using us4    = __attribute__((ext_vector_type(4))) unsigned short;
using f32x4  = __attribute__((ext_vector_type(4))) float;
typedef unsigned int u32;
typedef unsigned short u16;

constexpr int NPARENT = 200000;
constexpr int NCHILD  = 300000;
constexpr int TR      = 128;         // tile rows (nodes per block)
constexpr int NTHR    = 512;         // 8 waves

__device__ __forceinline__ u16 f2bf(float x) {        // fp32 -> bf16 RNE
    u32 u = __builtin_bit_cast(u32, x);
    u32 r = (u + 0x7fffu + ((u >> 16) & 1u)) >> 16;
    return (u16)r;
}
__device__ __forceinline__ float bf2f(u16 x) {
    u32 u = ((u32)x) << 16;
    return __builtin_bit_cast(float, u);
}
// swizzled byte offset in a [rows][64 bf16] tile (row stride 128 B).
__device__ __forceinline__ int swz(int row, int byteInRow) {
    return row * 128 + (byteInRow ^ ((row & 7) << 4));
}

// ---------------- fused prep: weights + feat->bf16 + child idx fusion ------
__global__ __launch_bounds__(256)
void prep_all(const float* __restrict__ W1, const float* __restrict__ W2,
              const float* __restrict__ Wv1, const float* __restrict__ Wv2,
              const float* __restrict__ feat,
              const int* __restrict__ neigh_d1, const int* __restrict__ parent_idx,
              const float* __restrict__ split_gt,
              u16* __restrict__ Wt1, u16* __restrict__ Wt2,
              u16* __restrict__ Wv1t, u16* __restrict__ Wv2t,
              u16* __restrict__ featb, int* __restrict__ fused,
              int bW, int bF, int doFeat, int doFuse)
{
    const int b = blockIdx.x;
    if (b < bW) {
        int t = b * 256 + threadIdx.x;
        if (t < 576 * 64) {
            int k = t >> 6, c = t & 63;
            Wt1[c * 576 + k] = f2bf(W1[t]);
            Wt2[c * 576 + k] = f2bf(W2[t]);
        }
        if (t < 64 * 64) {
            int k = t >> 6, c = t & 63;
            Wv1t[c * 64 + k] = f2bf(Wv1[t]);
            Wv2t[c * 64 + k] = f2bf(Wv2[t]);
        }
    } else if (b < bW + bF) {
        if (!doFeat) return;
        int t = (b - bW) * 256 + threadIdx.x;
        if (t < NPARENT * 64 / 8) {
            const float4 a = *reinterpret_cast<const float4*>(feat + (size_t)t * 8);
            const float4 c = *reinterpret_cast<const float4*>(feat + (size_t)t * 8 + 4);
            short8 o;
            o[0]=(short)f2bf(a.x); o[1]=(short)f2bf(a.y); o[2]=(short)f2bf(a.z); o[3]=(short)f2bf(a.w);
            o[4]=(short)f2bf(c.x); o[5]=(short)f2bf(c.y); o[6]=(short)f2bf(c.z); o[7]=(short)f2bf(c.w);
            *reinterpret_cast<short8*>(featb + (size_t)t * 8) = o;
        }
    } else {
        if (!doFuse) return;
        int t = (b - bW - bF) * 256 + threadIdx.x;
        if (t < NCHILD * 9) {
            int g = neigh_d1[t];
            int e = -1;
            if (g >= 0) {
                int p = parent_idx[g];
                if (split_gt[p] != 0.0f) e = p;
            }
            fused[t] = e;
        }
    }
}

// ---------------- main fused conv + heads kernel ----------------
// MODE: 0 = parent fp32 feat (fallback)  1 = parent bf16 feat
//       2 = child fused idx              3 = child unfused (fallback)
template<int MODE>
__global__ __launch_bounds__(NTHR, 6)
void quad_mfma(const float*  __restrict__ src_f32,    // MODE 0
               const u16*    __restrict__ src_b16,    // MODE 1: featb; 2/3: h
               const int*    __restrict__ idx,        // 0/1/3: neigh; 2: fused
               const int*    __restrict__ parent_idx, // MODE 3 only
               const float*  __restrict__ split_gt,   // MODE 3 only
               const u16*    __restrict__ Wt,         // [64][576] bf16
               const float*  __restrict__ bvec,
               const float*  __restrict__ Ws,
               const u16*    __restrict__ Wvt,        // [64][64] bf16
               float* __restrict__ split_out,
               float* __restrict__ value_out,
               u16*   __restrict__ h_out,             // parent modes only
               int N)
{
    __shared__ u16 aL[2][TR * 64];   // gathered-A double buffer (swizzled)
    __shared__ u16 wL[2][64 * 64];   // W chunk double buffer

    const int tid  = threadIdx.x;
    const int lane = tid & 63;
    const int w    = tid >> 6;        // wave 0..7 -> rows w*16..w*16+15
    const int cq   = lane & 15;
    const int kh   = lane >> 4;
    const int base = blockIdx.x * TR;
    const int ln   = tid >> 2;        // A staging row 0..127
    const int s    = tid & 3;         // A staging 16-col sub-slot
    const int wrow = tid >> 3;        // W staging row 0..63
    const int ws8  = tid & 7;         // W staging 16B slot

    // ---- hoist all 9 gather indices for this staging row ----
    int gidx[9];
    #pragma unroll
    for (int j = 0; j < 9; ++j) gidx[j] = -1;
    if (base + ln < N) {
        #pragma unroll
        for (int j = 0; j < 9; ++j) gidx[j] = idx[(size_t)(base + ln) * 9 + j];
        if (MODE == 3) {
            #pragma unroll
            for (int j = 0; j < 9; ++j) {
                int g = gidx[j], e = -1;
                if (g >= 0) {
                    int p = parent_idx[g];
                    if (split_gt[p] != 0.0f) e = p;
                }
                gidx[j] = e;
            }
        }
    }

    // ---- staging registers: TWO A-sets (depth-2 prefetch), one W reg ----
    const short8 zero8 = short8{0,0,0,0,0,0,0,0};
    short8 avS[2][2];                 // bf16 A path
    float4 avP[2][4];                 // fp32 A fallback
    short8 wv1;                       // W staging reg (1 x 16B per thread)

    auto issueA = [&](int j, int set) {
        const int g = gidx[j];
        if (MODE == 0) {
            #pragma unroll
            for (int u = 0; u < 4; ++u) avP[set][u] = make_float4(0.f,0.f,0.f,0.f);
            if (g >= 0) {
                const float* sp = src_f32 + (size_t)g * 64 + s * 16;
                #pragma unroll
                for (int u = 0; u < 4; ++u)
                    avP[set][u] = *reinterpret_cast<const float4*>(sp + u * 4);
            }
        } else {
            if (g >= 0) {
                const u16* sp = src_b16 + (size_t)g * 64 + s * 16;
                avS[set][0] = *reinterpret_cast<const short8*>(sp);
                avS[set][1] = *reinterpret_cast<const short8*>(sp + 8);
            } else { avS[set][0] = zero8; avS[set][1] = zero8; }
        }
    };
    auto writeA = [&](int set, int buf) {
        char* aB = (char*)aL[buf];
        if (MODE == 0) {
            #pragma unroll
            for (int u = 0; u < 4; ++u) {
                us4 t4 = { f2bf(avP[set][u].x), f2bf(avP[set][u].y),
                           f2bf(avP[set][u].z), f2bf(avP[set][u].w) };
                *reinterpret_cast<us4*>(aB + swz(ln, s * 32 + u * 8)) = t4;
            }
        } else {
            *reinterpret_cast<short8*>(aB + swz(ln, s * 32))      = avS[set][0];
            *reinterpret_cast<short8*>(aB + swz(ln, s * 32 + 16)) = avS[set][1];
        }
    };
    auto issueW = [&](int j) {
        wv1 = *reinterpret_cast<const short8*>(
            Wt + (size_t)wrow * 576 + j * 64 + ws8 * 8);
    };
    auto writeW = [&](int buf) {
        *reinterpret_cast<short8*>((char*)wL[buf] + swz(wrow, ws8 * 16)) = wv1;
    };
    auto stageWv = [&]() {
        short8 a = *reinterpret_cast<const short8*>(Wvt + (size_t)wrow * 64 + ws8 * 8);
        *reinterpret_cast<short8*>((char*)wL[1] + swz(wrow, ws8 * 16)) = a;
    };

    // ---- accumulators: bias broadcast ----
    f32x4 acc[4];
    #pragma unroll
    for (int cf = 0; cf < 4; ++cf) {
        float b = bvec[cf * 16 + cq];
        acc[cf] = f32x4{b, b, b, b};
    }

    auto computeChunk = [&](int buf, f32x4* ac) {
        const char* aB = (const char*)aL[buf];
        const char* wB = (const char*)wL[buf];
        #pragma unroll
        for (int ks = 0; ks < 2; ++ks) {
            short8 afrag = *reinterpret_cast<const short8*>(
                aB + swz(w * 16 + cq, ks * 64 + kh * 16));
            #pragma unroll
            for (int cf = 0; cf < 4; ++cf) {
                short8 bfrag = *reinterpret_cast<const short8*>(
                    wB + swz(cf * 16 + cq, ks * 64 + kh * 16));
                ac[cf] = __builtin_amdgcn_mfma_f32_16x16x32_bf16(afrag, bfrag, ac[cf], 0, 0, 0);
            }
        }
    };

    // ---- prologue: A(0)->set0, A(1)->set1 in flight; A(0),W(0) -> LDS ----
    issueA(0, 0); issueA(1, 1); issueW(0);
    writeA(0, 0); writeW(0);
    __syncthreads();

    // ---- conv loop: 2 barriers/chunk, A prefetched 2 ahead ----
    for (int j = 0; j < 9; ++j) {
        if (j <= 6) issueA(j + 2, j & 1);
        if (j < 8) issueW(j + 1);
        computeChunk(j & 1, acc);
        __syncthreads();
        if (j < 8) {
            writeA((j + 1) & 1, (j + 1) & 1);
            writeW((j + 1) & 1);
        } else {
            // final chunk: stage head weights + relu'd hT into free buffers
            stageWv();
            char* hB = (char*)aL[1];
            #pragma unroll
            for (int cf = 0; cf < 4; ++cf)
                #pragma unroll
                for (int r = 0; r < 4; ++r) {
                    float hval = fmaxf(acc[cf][r], 0.f);
                    int row = w * 16 + kh * 4 + r;       // C/D: row=(l>>4)*4+r
                    int col = cf * 16 + cq;              //      col=l&15 (+16*cf)
                    *reinterpret_cast<u16*>(hB + swz(row, col * 2)) = f2bf(hval);
                }
        }
        __syncthreads();
    }

    // ---- value head: value = relu(h) @ Wv  (aL[1]=hT, wL[1]=Wv) ----
    f32x4 vacc[4];
    #pragma unroll
    for (int cf = 0; cf < 4; ++cf) vacc[cf] = f32x4{0.f, 0.f, 0.f, 0.f};
    computeChunk(1, vacc);

    #pragma unroll
    for (int cf = 0; cf < 4; ++cf)
        #pragma unroll
        for (int r = 0; r < 4; ++r) {
            int node = base + w * 16 + kh * 4 + r;
            if (node < N)
                value_out[(size_t)node * 64 + cf * 16 + cq] = vacc[cf][r];
        }

    // ---- parent: write bf16 h (ungated) to workspace, coalesced ----
    if (MODE == 0 || MODE == 1) {
        int node = base + ln;
        if (node < N) {
            const char* hB = (const char*)aL[1];
            short8 x0 = *reinterpret_cast<const short8*>(hB + swz(ln, s * 32));
            short8 x1 = *reinterpret_cast<const short8*>(hB + swz(ln, s * 32 + 16));
            u16* dst = h_out + (size_t)node * 64 + s * 16;
            *reinterpret_cast<short8*>(dst)     = x0;
            *reinterpret_cast<short8*>(dst + 8) = x1;
        }
    }

    // ---- split head: split[n] = dot(h[n], Ws) ----
    {
        const char* hB = (const char*)aL[1];
        float sp = 0.f;
        #pragma unroll
        for (int u2 = 0; u2 < 2; ++u2) {
            short8 hv = *reinterpret_cast<const short8*>(hB + swz(ln, s * 32 + u2 * 16));
            #pragma unroll
            for (int e = 0; e < 8; ++e)
                sp += bf2f((u16)hv[e]) * Ws[s * 16 + u2 * 8 + e];
        }
        sp += __shfl_xor(sp, 1);
        sp += __shfl_xor(sp, 2);
        if (s == 0) {
            int node = base + ln;
            if (node < N) split_out[node] = sp;
        }
    }
}

extern "C" void kernel_launch(void* const* d_in, const int* in_sizes, int n_in,
                              void* d_out, int out_size, void* d_ws, size_t ws_size,
                              hipStream_t stream) {
    const float* feat       = (const float*)d_in[0];
    const int*   neigh_d    = (const int*)d_in[1];
    const int*   neigh_d1   = (const int*)d_in[2];
    const int*   parent_idx = (const int*)d_in[3];
    const float* split_gt   = (const float*)d_in[4];
    const float* W1  = (const float*)d_in[5];
    const float* b1  = (const float*)d_in[6];
    const float* W2  = (const float*)d_in[7];
    const float* b2  = (const float*)d_in[8];
    const float* Ws1 = (const float*)d_in[9];
    const float* Wv1 = (const float*)d_in[10];
    const float* Ws2 = (const float*)d_in[11];
    const float* Wv2 = (const float*)d_in[12];

    float* out    = (float*)d_out;
    float* split1 = out;
    float* value1 = out + NPARENT;
    float* split2 = out + NPARENT + (size_t)NPARENT * 64;
    float* value2 = split2 + NCHILD;

    // ---- workspace layout ----
    u16* h_ws = (u16*)d_ws;                          // [200000][64] bf16, ungated
    u16* Wt1  = h_ws + (size_t)NPARENT * 64;
    u16* Wt2  = Wt1 + 576 * 64;
    u16* Wv1t = Wt2 + 576 * 64;
    u16* Wv2t = Wv1t + 64 * 64;
    u16* endW = Wv2t + 64 * 64;
    size_t offW_bytes = (size_t)(endW - (u16*)d_ws) * 2;

    int*  fused = (int*)((char*)d_ws + offW_bytes);  // [300000][9] int32
    size_t offF_bytes = offW_bytes + (size_t)NCHILD * 9 * 4;
    u16*  featb = (u16*)((char*)d_ws + offF_bytes);  // [200000][64] bf16
    size_t offB_bytes = offF_bytes + (size_t)NPARENT * 64 * 2;

    const bool useFused = ws_size >= offF_bytes;
    const bool useFeatb = ws_size >= offB_bytes;

    const int bW = 145;                              // 145*256 >= 576*64
    const int bF = (NPARENT * 64 / 8 + 255) / 256;   // feat bf16 conversion
    const int bI = (NCHILD * 9 + 255) / 256;         // idx fusion
    prep_all<<<bW + bF + bI, 256, 0, stream>>>(
        W1, W2, Wv1, Wv2, feat, neigh_d1, parent_idx, split_gt,
        Wt1, Wt2, Wv1t, Wv2t, featb, fused,
        bW, bF, useFeatb ? 1 : 0, useFused ? 1 : 0);

    const int gP = (NPARENT + TR - 1) / TR;
    const int gC = (NCHILD + TR - 1) / TR;

    if (useFeatb)
        quad_mfma<1><<<gP, NTHR, 0, stream>>>(
            nullptr, featb, neigh_d, nullptr, nullptr,
            Wt1, b1, Ws1, Wv1t, split1, value1, h_ws, NPARENT);
    else
        quad_mfma<0><<<gP, NTHR, 0, stream>>>(
            feat, nullptr, neigh_d, nullptr, nullptr,
            Wt1, b1, Ws1, Wv1t, split1, value1, h_ws, NPARENT);

    if (useFused)
        quad_mfma<2><<<gC, NTHR, 0, stream>>>(
            nullptr, h_ws, fused, nullptr, nullptr,
            Wt2, b2, Ws2, Wv2t, split2, value2, nullptr, NCHILD);
    else
        quad_mfma<3><<<gC, NTHR, 0, stream>>>(
            nullptr, h_ws, neigh_d1, parent_idx, split_gt,
            Wt2, b2, Ws2, Wv2t, split2, value2, nullptr, NCHILD);
}

// Round 11
// 173.941 us; speedup vs baseline: 1.0189x; 1.0189x over previous
//
#include <hip/hip_runtime.h>

// TreeDecoderTeacherForced — R10: R6 structure exactly (LDS-staged A+W, XOR
// swizzle, 64-row/256-thread tile, plain cached stores — NT reverted: +2x
// HBM write RMW; 512-thr tile reverted: launch-bounds spills) + the ONE clean
// change: no-drain barriers (s_waitcnt lgkmcnt(0); s_barrier) with a
// FIFO-correct issue schedule — iter j issues W(j+2) then A(j+3); tail
// writes chunk j+1 with compiler-derived vmcnt(8)/vmcnt(6). A-gathers stay
// in flight ~2.5 chunk periods (~10 loads/wave outstanding vs 6 before).

using short8 = __attribute__((ext_vector_type(8))) short;
using us4    = __attribute__((ext_vector_type(4))) unsigned short;
using f32x4  = __attribute__((ext_vector_type(4))) float;
typedef unsigned int u32;
typedef unsigned short u16;

constexpr int NPARENT = 200000;
constexpr int NCHILD  = 300000;

__device__ __forceinline__ void barrier_no_drain() {
    // LDS produce->consume visibility WITHOUT the vmcnt(0) global-load drain
    // __syncthreads() emits; global->reg staging is ordered by the compiler's
    // own register-dependence vmcnt waits.
    asm volatile("s_waitcnt lgkmcnt(0)" ::: "memory");
    __builtin_amdgcn_s_barrier();
}

__device__ __forceinline__ u16 f2bf(float x) {        // fp32 -> bf16 RNE
    u32 u = __builtin_bit_cast(u32, x);
    u32 r = (u + 0x7fffu + ((u >> 16) & 1u)) >> 16;
    return (u16)r;
}
__device__ __forceinline__ float bf2f(u16 x) {
    u32 u = ((u32)x) << 16;
    return __builtin_bit_cast(float, u);
}
// swizzled byte offset in a [64 rows][64 bf16] tile (row stride 128 B).
__device__ __forceinline__ int swz(int row, int byteInRow) {
    return row * 128 + (byteInRow ^ ((row & 7) << 4));
}

// ---------------- fused prep: weights + feat->bf16 + child idx fusion ------
__global__ __launch_bounds__(256)
void prep_all(const float* __restrict__ W1, const float* __restrict__ W2,
              const float* __restrict__ Wv1, const float* __restrict__ Wv2,
              const float* __restrict__ feat,
              const int* __restrict__ neigh_d1, const int* __restrict__ parent_idx,
              const float* __restrict__ split_gt,
              u16* __restrict__ Wt1, u16* __restrict__ Wt2,
              u16* __restrict__ Wv1t, u16* __restrict__ Wv2t,
              u16* __restrict__ featb, int* __restrict__ fused,
              int bW, int bF, int doFeat, int doFuse)
{
    const int b = blockIdx.x;
    if (b < bW) {
        int t = b * 256 + threadIdx.x;
        if (t < 576 * 64) {
            int k = t >> 6, c = t & 63;
            Wt1[c * 576 + k] = f2bf(W1[t]);
            Wt2[c * 576 + k] = f2bf(W2[t]);
        }
        if (t < 64 * 64) {
            int k = t >> 6, c = t & 63;
            Wv1t[c * 64 + k] = f2bf(Wv1[t]);
            Wv2t[c * 64 + k] = f2bf(Wv2[t]);
        }
    } else if (b < bW + bF) {
        if (!doFeat) return;
        int t = (b - bW) * 256 + threadIdx.x;
        if (t < NPARENT * 64 / 8) {
            const float4 a = *reinterpret_cast<const float4*>(feat + (size_t)t * 8);
            const float4 c = *reinterpret_cast<const float4*>(feat + (size_t)t * 8 + 4);
            short8 o;
            o[0]=(short)f2bf(a.x); o[1]=(short)f2bf(a.y); o[2]=(short)f2bf(a.z); o[3]=(short)f2bf(a.w);
            o[4]=(short)f2bf(c.x); o[5]=(short)f2bf(c.y); o[6]=(short)f2bf(c.z); o[7]=(short)f2bf(c.w);
            *reinterpret_cast<short8*>(featb + (size_t)t * 8) = o;
        }
    } else {
        if (!doFuse) return;
        int t = (b - bW - bF) * 256 + threadIdx.x;
        if (t < NCHILD * 9) {
            int g = neigh_d1[t];
            int e = -1;
            if (g >= 0) {
                int p = parent_idx[g];
                if (split_gt[p] != 0.0f) e = p;
            }
            fused[t] = e;
        }
    }
}

// ---------------- main fused conv + heads kernel ----------------
// MODE: 0 = parent fp32 feat (fallback)  1 = parent bf16 feat
//       2 = child fused idx              3 = child unfused (fallback)
template<int MODE>
__global__ __launch_bounds__(256, 5)
void quad_mfma(const float*  __restrict__ src_f32,    // MODE 0
               const u16*    __restrict__ src_b16,    // MODE 1: featb; 2/3: h
               const int*    __restrict__ idx,        // 0/1/3: neigh; 2: fused
               const int*    __restrict__ parent_idx, // MODE 3 only
               const float*  __restrict__ split_gt,   // MODE 3 only
               const u16*    __restrict__ Wt,         // [64][576] bf16
               const float*  __restrict__ bvec,
               const float*  __restrict__ Ws,
               const u16*    __restrict__ Wvt,        // [64][64] bf16
               float* __restrict__ split_out,
               float* __restrict__ value_out,
               u16*   __restrict__ h_out,             // parent modes only
               int N)
{
    __shared__ u16 aL[2][64 * 64];
    __shared__ u16 wL[2][64 * 64];

    const int tid  = threadIdx.x;
    const int lane = tid & 63;
    const int w    = tid >> 6;
    const int cq   = lane & 15;
    const int kh   = lane >> 4;
    const int base = blockIdx.x * 64;
    const int ln   = tid >> 2;        // staging row 0..63
    const int s    = tid & 3;         // staging 16-col sub-slot

    // ---- hoist all 9 gather indices for this staging row ----
    int gidx[9];
    #pragma unroll
    for (int j = 0; j < 9; ++j) gidx[j] = -1;
    if (base + ln < N) {
        #pragma unroll
        for (int j = 0; j < 9; ++j) gidx[j] = idx[(size_t)(base + ln) * 9 + j];
        if (MODE == 3) {
            #pragma unroll
            for (int j = 0; j < 9; ++j) {
                int g = gidx[j], e = -1;
                if (g >= 0) {
                    int p = parent_idx[g];
                    if (split_gt[p] != 0.0f) e = p;
                }
                gidx[j] = e;
            }
        }
    }

    // ---- staging registers: THREE A-sets (depth-3), TWO W-sets (depth-2) ----
    const short8 zero8 = short8{0,0,0,0,0,0,0,0};
    short8 avS[3][2];                 // bf16 A path
    float4 avP[3][4];                 // fp32 A fallback
    short8 wvS[2][2];                 // W staging regs

    auto issueA = [&](int j, int set) {
        const int g = gidx[j];
        if (MODE == 0) {
            #pragma unroll
            for (int u = 0; u < 4; ++u) avP[set][u] = make_float4(0.f,0.f,0.f,0.f);
            if (g >= 0) {
                const float* sp = src_f32 + (size_t)g * 64 + s * 16;
                #pragma unroll
                for (int u = 0; u < 4; ++u)
                    avP[set][u] = *reinterpret_cast<const float4*>(sp + u * 4);
            }
        } else {
            if (g >= 0) {
                const u16* sp = src_b16 + (size_t)g * 64 + s * 16;
                avS[set][0] = *reinterpret_cast<const short8*>(sp);
                avS[set][1] = *reinterpret_cast<const short8*>(sp + 8);
            } else { avS[set][0] = zero8; avS[set][1] = zero8; }
        }
    };
    auto writeA = [&](int set, int buf) {
        char* aB = (char*)aL[buf];
        if (MODE == 0) {
            #pragma unroll
            for (int u = 0; u < 4; ++u) {
                us4 t4 = { f2bf(avP[set][u].x), f2bf(avP[set][u].y),
                           f2bf(avP[set][u].z), f2bf(avP[set][u].w) };
                *reinterpret_cast<us4*>(aB + swz(ln, s * 32 + u * 8)) = t4;
            }
        } else {
            *reinterpret_cast<short8*>(aB + swz(ln, s * 32))      = avS[set][0];
            *reinterpret_cast<short8*>(aB + swz(ln, s * 32 + 16)) = avS[set][1];
        }
    };
    auto issueW = [&](int j, int set) {
        const u16* src = Wt + (size_t)ln * 576 + j * 64 + s * 16;
        wvS[set][0] = *reinterpret_cast<const short8*>(src);
        wvS[set][1] = *reinterpret_cast<const short8*>(src + 8);
    };
    auto writeW = [&](int set, int buf) {
        char* wB = (char*)wL[buf];
        *reinterpret_cast<short8*>(wB + swz(ln, s * 32))      = wvS[set][0];
        *reinterpret_cast<short8*>(wB + swz(ln, s * 32 + 16)) = wvS[set][1];
    };
    auto stageWv = [&]() {
        const u16* src = Wvt + (size_t)ln * 64 + s * 16;
        short8 a = *reinterpret_cast<const short8*>(src);
        short8 b = *reinterpret_cast<const short8*>(src + 8);
        char* wB = (char*)wL[1];
        *reinterpret_cast<short8*>(wB + swz(ln, s * 32))      = a;
        *reinterpret_cast<short8*>(wB + swz(ln, s * 32 + 16)) = b;
    };

    // ---- accumulators: bias broadcast ----
    f32x4 acc[4];
    #pragma unroll
    for (int cf = 0; cf < 4; ++cf) {
        float b = bvec[cf * 16 + cq];
        acc[cf] = f32x4{b, b, b, b};
    }

    auto computeChunk = [&](int buf, f32x4* ac) {
        const char* aB = (const char*)aL[buf];
        const char* wB = (const char*)wL[buf];
        #pragma unroll
        for (int ks = 0; ks < 2; ++ks) {
            short8 afrag = *reinterpret_cast<const short8*>(
                aB + swz(w * 16 + cq, ks * 64 + kh * 16));
            #pragma unroll
            for (int cf = 0; cf < 4; ++cf) {
                short8 bfrag = *reinterpret_cast<const short8*>(
                    wB + swz(cf * 16 + cq, ks * 64 + kh * 16));
                ac[cf] = __builtin_amdgcn_mfma_f32_16x16x32_bf16(afrag, bfrag, ac[cf], 0, 0, 0);
            }
        }
    };

    // ---- prologue ----
    // A(0),W(0) -> LDS immediately; then A(1),W(1),A(2) issued into flight.
    issueA(0, 0); issueW(0, 0);
    writeA(0, 0); writeW(0, 0);
    issueA(1, 1); issueW(1, 1); issueA(2, 2);
    barrier_no_drain();

    // ---- conv loop: no-drain barriers, FIFO-correct deep prefetch ----
    // iter j: issue W(j+2)->wset(j&1), A(j+3)->set(j&1... (j+3)%3=j%3) |
    //         compute buf(j&1) | bar | writeA(j+1) [vmcnt~8] writeW(j+1)
    //         [vmcnt~6; A(j+2),A(j+3),W(j+2) keep flying] | bar
    for (int j = 0; j < 9; ++j) {
        if (j <= 6) issueW(j + 2, j & 1);
        if (j <= 5) issueA(j + 3, j % 3);
        computeChunk(j & 1, acc);
        barrier_no_drain();
        if (j < 8) {
            writeA((j + 1) % 3, (j + 1) & 1);
            writeW((j + 1) & 1, (j + 1) & 1);
        } else {
            // final chunk: stage head weights + relu'd hT into free buffers
            stageWv();
            char* hB = (char*)aL[1];
            #pragma unroll
            for (int cf = 0; cf < 4; ++cf)
                #pragma unroll
                for (int r = 0; r < 4; ++r) {
                    float hval = fmaxf(acc[cf][r], 0.f);
                    int row = w * 16 + kh * 4 + r;       // C/D: row=(l>>4)*4+r
                    int col = cf * 16 + cq;              //      col=l&15 (+16*cf)
                    *reinterpret_cast<u16*>(hB + swz(row, col * 2)) = f2bf(hval);
                }
        }
        barrier_no_drain();
    }

    // ---- value head: value = relu(h) @ Wv  (aL[1]=hT, wL[1]=Wv) ----
    f32x4 vacc[4];
    #pragma unroll
    for (int cf = 0; cf < 4; ++cf) vacc[cf] = f32x4{0.f, 0.f, 0.f, 0.f};
    computeChunk(1, vacc);

    #pragma unroll
    for (int cf = 0; cf < 4; ++cf)
        #pragma unroll
        for (int r = 0; r < 4; ++r) {
            int node = base + w * 16 + kh * 4 + r;
            if (node < N)
                value_out[(size_t)node * 64 + cf * 16 + cq] = vacc[cf][r];
        }

    // ---- parent: write bf16 h (ungated) to workspace, coalesced ----
    if (MODE == 0 || MODE == 1) {
        int node = base + ln;
        if (node < N) {
            const char* hB = (const char*)aL[1];
            short8 x0 = *reinterpret_cast<const short8*>(hB + swz(ln, s * 32));
            short8 x1 = *reinterpret_cast<const short8*>(hB + swz(ln, s * 32 + 16));
            u16* dst = h_out + (size_t)node * 64 + s * 16;
            *reinterpret_cast<short8*>(dst)     = x0;
            *reinterpret_cast<short8*>(dst + 8) = x1;
        }
    }

    // ---- split head: split[n] = dot(h[n], Ws) ----
    {
        const char* hB = (const char*)aL[1];
        float sp = 0.f;
        #pragma unroll
        for (int u2 = 0; u2 < 2; ++u2) {
            short8 hv = *reinterpret_cast<const short8*>(hB + swz(ln, s * 32 + u2 * 16));
            #pragma unroll
            for (int e = 0; e < 8; ++e)
                sp += bf2f((u16)hv[e]) * Ws[s * 16 + u2 * 8 + e];
        }
        sp += __shfl_xor(sp, 1);
        sp += __shfl_xor(sp, 2);
        if (s == 0) {
            int node = base + ln;
            if (node < N) split_out[node] = sp;
        }
    }
}

extern "C" void kernel_launch(void* const* d_in, const int* in_sizes, int n_in,
                              void* d_out, int out_size, void* d_ws, size_t ws_size,
                              hipStream_t stream) {
    const float* feat       = (const float*)d_in[0];
    const int*   neigh_d    = (const int*)d_in[1];
    const int*   neigh_d1   = (const int*)d_in[2];
    const int*   parent_idx = (const int*)d_in[3];
    const float* split_gt   = (const float*)d_in[4];
    const float* W1  = (const float*)d_in[5];
    const float* b1  = (const float*)d_in[6];
    const float* W2  = (const float*)d_in[7];
    const float* b2  = (const float*)d_in[8];
    const float* Ws1 = (const float*)d_in[9];
    const float* Wv1 = (const float*)d_in[10];
    const float* Ws2 = (const float*)d_in[11];
    const float* Wv2 = (const float*)d_in[12];

    float* out    = (float*)d_out;
    float* split1 = out;
    float* value1 = out + NPARENT;
    float* split2 = out + NPARENT + (size_t)NPARENT * 64;
    float* value2 = split2 + NCHILD;

    // ---- workspace layout ----
    u16* h_ws = (u16*)d_ws;                          // [200000][64] bf16, ungated
    u16* Wt1  = h_ws + (size_t)NPARENT * 64;
    u16* Wt2  = Wt1 + 576 * 64;
    u16* Wv1t = Wt2 + 576 * 64;
    u16* Wv2t = Wv1t + 64 * 64;
    u16* endW = Wv2t + 64 * 64;
    size_t offW_bytes = (size_t)(endW - (u16*)d_ws) * 2;

    int*  fused = (int*)((char*)d_ws + offW_bytes);  // [300000][9] int32
    size_t offF_bytes = offW_bytes + (size_t)NCHILD * 9 * 4;
    u16*  featb = (u16*)((char*)d_ws + offF_bytes);  // [200000][64] bf16
    size_t offB_bytes = offF_bytes + (size_t)NPARENT * 64 * 2;

    const bool useFused = ws_size >= offF_bytes;
    const bool useFeatb = ws_size >= offB_bytes;

    const int bW = 145;                              // 145*256 >= 576*64
    const int bF = (NPARENT * 64 / 8 + 255) / 256;   // feat bf16 conversion
    const int bI = (NCHILD * 9 + 255) / 256;         // idx fusion
    prep_all<<<bW + bF + bI, 256, 0, stream>>>(
        W1, W2, Wv1, Wv2, feat, neigh_d1, parent_idx, split_gt,
        Wt1, Wt2, Wv1t, Wv2t, featb, fused,
        bW, bF, useFeatb ? 1 : 0, useFused ? 1 : 0);

    if (useFeatb)
        quad_mfma<1><<<NPARENT / 64, 256, 0, stream>>>(
            nullptr, featb, neigh_d, nullptr, nullptr,
            Wt1, b1, Ws1, Wv1t, split1, value1, h_ws, NPARENT);
    else
        quad_mfma<0><<<NPARENT / 64, 256, 0, stream>>>(
            feat, nullptr, neigh_d, nullptr, nullptr,
            Wt1, b1, Ws1, Wv1t, split1, value1, h_ws, NPARENT);

    if (useFused)
        quad_mfma<2><<<(NCHILD + 63) / 64, 256, 0, stream>>>(
            nullptr, h_ws, fused, nullptr, nullptr,
            Wt2, b2, Ws2, Wv2t, split2, value2, nullptr, NCHILD);
    else
        quad_mfma<3><<<(NCHILD + 63) / 64, 256, 0, stream>>>(
            nullptr, h_ws, neigh_d1, parent_idx, split_gt,
            Wt2, b2, Ws2, Wv2t, split2, value2, nullptr, NCHILD);
}

// Round 12
// 140.467 us; speedup vs baseline: 1.2617x; 1.2383x over previous
//
#include <hip/hip_runtime.h>

// TreeDecoderTeacherForced — R11: R6 structure (LDS-staged A+W, XOR swizzle,
// __syncthreads, depth-2 A prefetch, fused child idx, bf16 feat) with a
// 128-row x 256-thread tile: each thread stages TWO rows' worth (64 B/issue,
// 4 VMEM instr) -> 2x outstanding gathers per wave at the same 12 waves/CU
// (48 KB LDS, 3 blocks/CU). Conv loop fully unrolled so all staging-register
// indices are compile-time static (R10 lesson: runtime-indexed ext_vector
// arrays -> scratch -> +90 MB HBM traffic).

using short8 = __attribute__((ext_vector_type(8))) short;
using us4    = __attribute__((ext_vector_type(4))) unsigned short;
using f32x4  = __attribute__((ext_vector_type(4))) float;
typedef unsigned int u32;
typedef unsigned short u16;

constexpr int NPARENT = 200000;
constexpr int NCHILD  = 300000;
constexpr int TR      = 128;       // nodes per block
constexpr int NTHR    = 256;       // 4 waves

__device__ __forceinline__ u16 f2bf(float x) {        // fp32 -> bf16 RNE
    u32 u = __builtin_bit_cast(u32, x);
    u32 r = (u + 0x7fffu + ((u >> 16) & 1u)) >> 16;
    return (u16)r;
}
__device__ __forceinline__ float bf2f(u16 x) {
    u32 u = ((u32)x) << 16;
    return __builtin_bit_cast(float, u);
}
// swizzled byte offset in a [rows][64 bf16] tile (row stride 128 B).
__device__ __forceinline__ int swz(int row, int byteInRow) {
    return row * 128 + (byteInRow ^ ((row & 7) << 4));
}

// ---------------- fused prep: weights + feat->bf16 + child idx fusion ------
__global__ __launch_bounds__(256)
void prep_all(const float* __restrict__ W1, const float* __restrict__ W2,
              const float* __restrict__ Wv1, const float* __restrict__ Wv2,
              const float* __restrict__ feat,
              const int* __restrict__ neigh_d1, const int* __restrict__ parent_idx,
              const float* __restrict__ split_gt,
              u16* __restrict__ Wt1, u16* __restrict__ Wt2,
              u16* __restrict__ Wv1t, u16* __restrict__ Wv2t,
              u16* __restrict__ featb, int* __restrict__ fused,
              int bW, int bF, int doFeat, int doFuse)
{
    const int b = blockIdx.x;
    if (b < bW) {
        int t = b * 256 + threadIdx.x;
        if (t < 576 * 64) {
            int k = t >> 6, c = t & 63;
            Wt1[c * 576 + k] = f2bf(W1[t]);
            Wt2[c * 576 + k] = f2bf(W2[t]);
        }
        if (t < 64 * 64) {
            int k = t >> 6, c = t & 63;
            Wv1t[c * 64 + k] = f2bf(Wv1[t]);
            Wv2t[c * 64 + k] = f2bf(Wv2[t]);
        }
    } else if (b < bW + bF) {
        if (!doFeat) return;
        int t = (b - bW) * 256 + threadIdx.x;
        if (t < NPARENT * 64 / 8) {
            const float4 a = *reinterpret_cast<const float4*>(feat + (size_t)t * 8);
            const float4 c = *reinterpret_cast<const float4*>(feat + (size_t)t * 8 + 4);
            short8 o;
            o[0]=(short)f2bf(a.x); o[1]=(short)f2bf(a.y); o[2]=(short)f2bf(a.z); o[3]=(short)f2bf(a.w);
            o[4]=(short)f2bf(c.x); o[5]=(short)f2bf(c.y); o[6]=(short)f2bf(c.z); o[7]=(short)f2bf(c.w);
            *reinterpret_cast<short8*>(featb + (size_t)t * 8) = o;
        }
    } else {
        if (!doFuse) return;
        int t = (b - bW - bF) * 256 + threadIdx.x;
        if (t < NCHILD * 9) {
            int g = neigh_d1[t];
            int e = -1;
            if (g >= 0) {
                int p = parent_idx[g];
                if (split_gt[p] != 0.0f) e = p;
            }
            fused[t] = e;
        }
    }
}

// ---------------- main fused conv + heads kernel ----------------
// MODE: 0 = parent fp32 feat (fallback)  1 = parent bf16 feat
//       2 = child fused idx              3 = child unfused (fallback)
template<int MODE>
__global__ __launch_bounds__(NTHR, 3)
void quad_mfma(const float*  __restrict__ src_f32,    // MODE 0
               const u16*    __restrict__ src_b16,    // MODE 1: featb; 2/3: h
               const int*    __restrict__ idx,        // 0/1/3: neigh; 2: fused
               const int*    __restrict__ parent_idx, // MODE 3 only
               const float*  __restrict__ split_gt,   // MODE 3 only
               const u16*    __restrict__ Wt,         // [64][576] bf16
               const float*  __restrict__ bvec,
               const float*  __restrict__ Ws,
               const u16*    __restrict__ Wvt,        // [64][64] bf16
               float* __restrict__ split_out,
               float* __restrict__ value_out,
               u16*   __restrict__ h_out,             // parent modes only
               int N)
{
    __shared__ u16 aL[2][TR * 64];   // 2 x 16 KB gathered-A (swizzled)
    __shared__ u16 wL[2][64 * 64];   // 2 x 8 KB W chunk

    const int tid  = threadIdx.x;
    const int lane = tid & 63;
    const int w    = tid >> 6;        // wave 0..3 -> rows w*32..w*32+31
    const int cq   = lane & 15;
    const int kh   = lane >> 4;
    const int base = blockIdx.x * TR;
    const int ln   = tid >> 1;        // A staging row 0..127
    const int s    = tid & 1;         // A staging half-row (64 B)
    const int wrow = tid >> 2;        // W staging row 0..63
    const int ws4  = tid & 3;         // W staging 32 B slot

    // ---- hoist all 9 gather indices for this staging row ----
    int gidx[9];
    #pragma unroll
    for (int j = 0; j < 9; ++j) gidx[j] = -1;
    if (base + ln < N) {
        #pragma unroll
        for (int j = 0; j < 9; ++j) gidx[j] = idx[(size_t)(base + ln) * 9 + j];
        if (MODE == 3) {
            #pragma unroll
            for (int j = 0; j < 9; ++j) {
                int g = gidx[j], e = -1;
                if (g >= 0) {
                    int p = parent_idx[g];
                    if (split_gt[p] != 0.0f) e = p;
                }
                gidx[j] = e;
            }
        }
    }

    // ---- staging registers: TWO A-sets (depth-2), one W set ----
    const short8 zero8 = short8{0,0,0,0,0,0,0,0};
    short8 avS[2][4];                 // bf16 A path: 64 B per issue
    float4 avP[2][8];                 // fp32 A fallback: 128 B per issue
    short8 wv2[2];                    // W staging regs (32 B)

    auto issueA = [&](int j, int set) {
        const int g = gidx[j];
        if (MODE == 0) {
            #pragma unroll
            for (int u = 0; u < 8; ++u) avP[set][u] = make_float4(0.f,0.f,0.f,0.f);
            if (g >= 0) {
                const float* sp = src_f32 + (size_t)g * 64 + s * 32;
                #pragma unroll
                for (int u = 0; u < 8; ++u)
                    avP[set][u] = *reinterpret_cast<const float4*>(sp + u * 4);
            }
        } else {
            if (g >= 0) {
                const u16* sp = src_b16 + (size_t)g * 64 + s * 32;
                #pragma unroll
                for (int u = 0; u < 4; ++u)
                    avS[set][u] = *reinterpret_cast<const short8*>(sp + u * 8);
            } else {
                #pragma unroll
                for (int u = 0; u < 4; ++u) avS[set][u] = zero8;
            }
        }
    };
    auto writeA = [&](int set, int buf) {
        char* aB = (char*)aL[buf];
        if (MODE == 0) {
            #pragma unroll
            for (int u = 0; u < 8; ++u) {
                us4 t4 = { f2bf(avP[set][u].x), f2bf(avP[set][u].y),
                           f2bf(avP[set][u].z), f2bf(avP[set][u].w) };
                *reinterpret_cast<us4*>(aB + swz(ln, s * 64 + u * 8)) = t4;
            }
        } else {
            #pragma unroll
            for (int u = 0; u < 4; ++u)
                *reinterpret_cast<short8*>(aB + swz(ln, s * 64 + u * 16)) = avS[set][u];
        }
    };
    auto issueW = [&](int j) {
        const u16* src = Wt + (size_t)wrow * 576 + j * 64 + ws4 * 16;
        wv2[0] = *reinterpret_cast<const short8*>(src);
        wv2[1] = *reinterpret_cast<const short8*>(src + 8);
    };
    auto writeW = [&](int buf) {
        char* wB = (char*)wL[buf];
        *reinterpret_cast<short8*>(wB + swz(wrow, ws4 * 32))      = wv2[0];
        *reinterpret_cast<short8*>(wB + swz(wrow, ws4 * 32 + 16)) = wv2[1];
    };
    auto stageWv = [&]() {
        const u16* src = Wvt + (size_t)wrow * 64 + ws4 * 16;
        short8 a = *reinterpret_cast<const short8*>(src);
        short8 b = *reinterpret_cast<const short8*>(src + 8);
        char* wB = (char*)wL[1];
        *reinterpret_cast<short8*>(wB + swz(wrow, ws4 * 32))      = a;
        *reinterpret_cast<short8*>(wB + swz(wrow, ws4 * 32 + 16)) = b;
    };

    // ---- accumulators: bias broadcast; per wave 2 row-frags x 4 col-frags --
    f32x4 acc[2][4];
    #pragma unroll
    for (int ar = 0; ar < 2; ++ar)
        #pragma unroll
        for (int cf = 0; cf < 4; ++cf) {
            float b = bvec[cf * 16 + cq];
            acc[ar][cf] = f32x4{b, b, b, b};
        }

    auto computeChunk = [&](int buf, f32x4 (*ac)[4]) {
        const char* aB = (const char*)aL[buf];
        const char* wB = (const char*)wL[buf];
        #pragma unroll
        for (int ks = 0; ks < 2; ++ks)
            #pragma unroll
            for (int ar = 0; ar < 2; ++ar) {
                short8 afrag = *reinterpret_cast<const short8*>(
                    aB + swz(w * 32 + ar * 16 + cq, ks * 64 + kh * 16));
                #pragma unroll
                for (int cf = 0; cf < 4; ++cf) {
                    short8 bfrag = *reinterpret_cast<const short8*>(
                        wB + swz(cf * 16 + cq, ks * 64 + kh * 16));
                    ac[ar][cf] = __builtin_amdgcn_mfma_f32_16x16x32_bf16(
                        afrag, bfrag, ac[ar][cf], 0, 0, 0);
                }
            }
    };

    // ---- prologue: A(0),A(1) in flight; A(0),W(0) -> LDS ----
    issueA(0, 0); issueA(1, 1); issueW(0);
    writeA(0, 0); writeW(0);
    __syncthreads();

    // ---- conv loop (fully unrolled): 2 barriers/chunk, A depth-2 ----
    #pragma unroll
    for (int j = 0; j < 9; ++j) {
        if (j <= 6) issueA(j + 2, j & 1);
        if (j < 8) issueW(j + 1);
        computeChunk(j & 1, acc);
        __syncthreads();
        if (j < 8) {
            writeA((j + 1) & 1, (j + 1) & 1);
            writeW((j + 1) & 1);
        } else {
            // final chunk: stage head weights + relu'd hT into free buffers
            stageWv();
            char* hB = (char*)aL[1];
            #pragma unroll
            for (int ar = 0; ar < 2; ++ar)
                #pragma unroll
                for (int cf = 0; cf < 4; ++cf)
                    #pragma unroll
                    for (int r = 0; r < 4; ++r) {
                        float hval = fmaxf(acc[ar][cf][r], 0.f);
                        int row = w * 32 + ar * 16 + kh * 4 + r;  // C/D layout
                        int col = cf * 16 + cq;
                        *reinterpret_cast<u16*>(hB + swz(row, col * 2)) = f2bf(hval);
                    }
        }
        __syncthreads();
    }

    // ---- value head: value = relu(h) @ Wv  (aL[1]=hT, wL[1]=Wv) ----
    f32x4 vacc[2][4];
    #pragma unroll
    for (int ar = 0; ar < 2; ++ar)
        #pragma unroll
        for (int cf = 0; cf < 4; ++cf) vacc[ar][cf] = f32x4{0.f, 0.f, 0.f, 0.f};
    computeChunk(1, vacc);

    #pragma unroll
    for (int ar = 0; ar < 2; ++ar)
        #pragma unroll
        for (int cf = 0; cf < 4; ++cf)
            #pragma unroll
            for (int r = 0; r < 4; ++r) {
                int node = base + w * 32 + ar * 16 + kh * 4 + r;
                if (node < N)
                    value_out[(size_t)node * 64 + cf * 16 + cq] = vacc[ar][cf][r];
            }

    // ---- parent: write bf16 h (ungated) to workspace, coalesced ----
    if (MODE == 0 || MODE == 1) {
        int node = base + ln;
        if (node < N) {
            const char* hB = (const char*)aL[1];
            u16* dst = h_out + (size_t)node * 64 + s * 32;
            #pragma unroll
            for (int u = 0; u < 4; ++u) {
                short8 x = *reinterpret_cast<const short8*>(hB + swz(ln, s * 64 + u * 16));
                *reinterpret_cast<short8*>(dst + u * 8) = x;
            }
        }
    }

    // ---- split head: split[n] = dot(h[n], Ws); 2 threads per node ----
    {
        const char* hB = (const char*)aL[1];
        float sp = 0.f;
        #pragma unroll
        for (int u2 = 0; u2 < 4; ++u2) {
            short8 hv = *reinterpret_cast<const short8*>(hB + swz(ln, s * 64 + u2 * 16));
            #pragma unroll
            for (int e = 0; e < 8; ++e)
                sp += bf2f((u16)hv[e]) * Ws[s * 32 + u2 * 8 + e];
        }
        sp += __shfl_xor(sp, 1);
        if (s == 0) {
            int node = base + ln;
            if (node < N) split_out[node] = sp;
        }
    }
}

extern "C" void kernel_launch(void* const* d_in, const int* in_sizes, int n_in,
                              void* d_out, int out_size, void* d_ws, size_t ws_size,
                              hipStream_t stream) {
    const float* feat       = (const float*)d_in[0];
    const int*   neigh_d    = (const int*)d_in[1];
    const int*   neigh_d1   = (const int*)d_in[2];
    const int*   parent_idx = (const int*)d_in[3];
    const float* split_gt   = (const float*)d_in[4];
    const float* W1  = (const float*)d_in[5];
    const float* b1  = (const float*)d_in[6];
    const float* W2  = (const float*)d_in[7];
    const float* b2  = (const float*)d_in[8];
    const float* Ws1 = (const float*)d_in[9];
    const float* Wv1 = (const float*)d_in[10];
    const float* Ws2 = (const float*)d_in[11];
    const float* Wv2 = (const float*)d_in[12];

    float* out    = (float*)d_out;
    float* split1 = out;
    float* value1 = out + NPARENT;
    float* split2 = out + NPARENT + (size_t)NPARENT * 64;
    float* value2 = split2 + NCHILD;

    // ---- workspace layout ----
    u16* h_ws = (u16*)d_ws;                          // [200000][64] bf16, ungated
    u16* Wt1  = h_ws + (size_t)NPARENT * 64;
    u16* Wt2  = Wt1 + 576 * 64;
    u16* Wv1t = Wt2 + 576 * 64;
    u16* Wv2t = Wv1t + 64 * 64;
    u16* endW = Wv2t + 64 * 64;
    size_t offW_bytes = (size_t)(endW - (u16*)d_ws) * 2;

    int*  fused = (int*)((char*)d_ws + offW_bytes);  // [300000][9] int32
    size_t offF_bytes = offW_bytes + (size_t)NCHILD * 9 * 4;
    u16*  featb = (u16*)((char*)d_ws + offF_bytes);  // [200000][64] bf16
    size_t offB_bytes = offF_bytes + (size_t)NPARENT * 64 * 2;

    const bool useFused = ws_size >= offF_bytes;
    const bool useFeatb = ws_size >= offB_bytes;

    const int bW = 145;                              // 145*256 >= 576*64
    const int bF = (NPARENT * 64 / 8 + 255) / 256;   // feat bf16 conversion
    const int bI = (NCHILD * 9 + 255) / 256;         // idx fusion
    prep_all<<<bW + bF + bI, 256, 0, stream>>>(
        W1, W2, Wv1, Wv2, feat, neigh_d1, parent_idx, split_gt,
        Wt1, Wt2, Wv1t, Wv2t, featb, fused,
        bW, bF, useFeatb ? 1 : 0, useFused ? 1 : 0);

    const int gP = (NPARENT + TR - 1) / TR;
    const int gC = (NCHILD + TR - 1) / TR;

    if (useFeatb)
        quad_mfma<1><<<gP, NTHR, 0, stream>>>(
            nullptr, featb, neigh_d, nullptr, nullptr,
            Wt1, b1, Ws1, Wv1t, split1, value1, h_ws, NPARENT);
    else
        quad_mfma<0><<<gP, NTHR, 0, stream>>>(
            feat, nullptr, neigh_d, nullptr, nullptr,
            Wt1, b1, Ws1, Wv1t, split1, value1, h_ws, NPARENT);

    if (useFused)
        quad_mfma<2><<<gC, NTHR, 0, stream>>>(
            nullptr, h_ws, fused, nullptr, nullptr,
            Wt2, b2, Ws2, Wv2t, split2, value2, nullptr, NCHILD);
    else
        quad_mfma<3><<<gC, NTHR, 0, stream>>>(
            nullptr, h_ws, neigh_d1, parent_idx, split_gt,
            Wt2, b2, Ws2, Wv2t, split2, value2, nullptr, NCHILD);
}

// Round 13
// 139.635 us; speedup vs baseline: 1.2692x; 1.0060x over previous
//
#include <hip/hip_runtime.h>

// TreeDecoderTeacherForced — R12: R11 EXACTLY (128-row/256-thr tile, 2 rows
// per thread staging, LDS-staged A+W, XOR swizzle, depth-2 A prefetch, fully
// unrolled conv loop, fused child idx, bf16 feat, plain cached stores) with
// ONE change: chunk barriers are s_waitcnt lgkmcnt(0) + s_barrier instead of
// __syncthreads() — removing the vmcnt(0) drain so the depth-2 A-gather
// prefetch actually stays in flight across barriers (~2 chunk periods).
// Clean single-variable test: R8 confounded this with NT-store write RMW,
// R10 with runtime-indexed staging scratch.

using short8 = __attribute__((ext_vector_type(8))) short;
using us4    = __attribute__((ext_vector_type(4))) unsigned short;
using f32x4  = __attribute__((ext_vector_type(4))) float;
typedef unsigned int u32;
typedef unsigned short u16;

constexpr int NPARENT = 200000;
constexpr int NCHILD  = 300000;
constexpr int TR      = 128;       // nodes per block
constexpr int NTHR    = 256;       // 4 waves

__device__ __forceinline__ void barrier_no_drain() {
    // LDS produce->consume visibility WITHOUT the vmcnt(0) global-load drain
    // __syncthreads() emits; global->reg staging is ordered by the compiler's
    // own register-dependence vmcnt waits.
    asm volatile("s_waitcnt lgkmcnt(0)" ::: "memory");
    __builtin_amdgcn_s_barrier();
}

__device__ __forceinline__ u16 f2bf(float x) {        // fp32 -> bf16 RNE
    u32 u = __builtin_bit_cast(u32, x);
    u32 r = (u + 0x7fffu + ((u >> 16) & 1u)) >> 16;
    return (u16)r;
}
__device__ __forceinline__ float bf2f(u16 x) {
    u32 u = ((u32)x) << 16;
    return __builtin_bit_cast(float, u);
}
// swizzled byte offset in a [rows][64 bf16] tile (row stride 128 B).
__device__ __forceinline__ int swz(int row, int byteInRow) {
    return row * 128 + (byteInRow ^ ((row & 7) << 4));
}

// ---------------- fused prep: weights + feat->bf16 + child idx fusion ------
__global__ __launch_bounds__(256)
void prep_all(const float* __restrict__ W1, const float* __restrict__ W2,
              const float* __restrict__ Wv1, const float* __restrict__ Wv2,
              const float* __restrict__ feat,
              const int* __restrict__ neigh_d1, const int* __restrict__ parent_idx,
              const float* __restrict__ split_gt,
              u16* __restrict__ Wt1, u16* __restrict__ Wt2,
              u16* __restrict__ Wv1t, u16* __restrict__ Wv2t,
              u16* __restrict__ featb, int* __restrict__ fused,
              int bW, int bF, int doFeat, int doFuse)
{
    const int b = blockIdx.x;
    if (b < bW) {
        int t = b * 256 + threadIdx.x;
        if (t < 576 * 64) {
            int k = t >> 6, c = t & 63;
            Wt1[c * 576 + k] = f2bf(W1[t]);
            Wt2[c * 576 + k] = f2bf(W2[t]);
        }
        if (t < 64 * 64) {
            int k = t >> 6, c = t & 63;
            Wv1t[c * 64 + k] = f2bf(Wv1[t]);
            Wv2t[c * 64 + k] = f2bf(Wv2[t]);
        }
    } else if (b < bW + bF) {
        if (!doFeat) return;
        int t = (b - bW) * 256 + threadIdx.x;
        if (t < NPARENT * 64 / 8) {
            const float4 a = *reinterpret_cast<const float4*>(feat + (size_t)t * 8);
            const float4 c = *reinterpret_cast<const float4*>(feat + (size_t)t * 8 + 4);
            short8 o;
            o[0]=(short)f2bf(a.x); o[1]=(short)f2bf(a.y); o[2]=(short)f2bf(a.z); o[3]=(short)f2bf(a.w);
            o[4]=(short)f2bf(c.x); o[5]=(short)f2bf(c.y); o[6]=(short)f2bf(c.z); o[7]=(short)f2bf(c.w);
            *reinterpret_cast<short8*>(featb + (size_t)t * 8) = o;
        }
    } else {
        if (!doFuse) return;
        int t = (b - bW - bF) * 256 + threadIdx.x;
        if (t < NCHILD * 9) {
            int g = neigh_d1[t];
            int e = -1;
            if (g >= 0) {
                int p = parent_idx[g];
                if (split_gt[p] != 0.0f) e = p;
            }
            fused[t] = e;
        }
    }
}

// ---------------- main fused conv + heads kernel ----------------
// MODE: 0 = parent fp32 feat (fallback)  1 = parent bf16 feat
//       2 = child fused idx              3 = child unfused (fallback)
template<int MODE>
__global__ __launch_bounds__(NTHR, 3)
void quad_mfma(const float*  __restrict__ src_f32,    // MODE 0
               const u16*    __restrict__ src_b16,    // MODE 1: featb; 2/3: h
               const int*    __restrict__ idx,        // 0/1/3: neigh; 2: fused
               const int*    __restrict__ parent_idx, // MODE 3 only
               const float*  __restrict__ split_gt,   // MODE 3 only
               const u16*    __restrict__ Wt,         // [64][576] bf16
               const float*  __restrict__ bvec,
               const float*  __restrict__ Ws,
               const u16*    __restrict__ Wvt,        // [64][64] bf16
               float* __restrict__ split_out,
               float* __restrict__ value_out,
               u16*   __restrict__ h_out,             // parent modes only
               int N)
{
    __shared__ u16 aL[2][TR * 64];   // 2 x 16 KB gathered-A (swizzled)
    __shared__ u16 wL[2][64 * 64];   // 2 x 8 KB W chunk

    const int tid  = threadIdx.x;
    const int lane = tid & 63;
    const int w    = tid >> 6;        // wave 0..3 -> rows w*32..w*32+31
    const int cq   = lane & 15;
    const int kh   = lane >> 4;
    const int base = blockIdx.x * TR;
    const int ln   = tid >> 1;        // A staging row 0..127
    const int s    = tid & 1;         // A staging half-row (64 B)
    const int wrow = tid >> 2;        // W staging row 0..63
    const int ws4  = tid & 3;         // W staging 32 B slot

    // ---- hoist all 9 gather indices for this staging row ----
    int gidx[9];
    #pragma unroll
    for (int j = 0; j < 9; ++j) gidx[j] = -1;
    if (base + ln < N) {
        #pragma unroll
        for (int j = 0; j < 9; ++j) gidx[j] = idx[(size_t)(base + ln) * 9 + j];
        if (MODE == 3) {
            #pragma unroll
            for (int j = 0; j < 9; ++j) {
                int g = gidx[j], e = -1;
                if (g >= 0) {
                    int p = parent_idx[g];
                    if (split_gt[p] != 0.0f) e = p;
                }
                gidx[j] = e;
            }
        }
    }

    // ---- staging registers: TWO A-sets (depth-2), one W set ----
    const short8 zero8 = short8{0,0,0,0,0,0,0,0};
    short8 avS[2][4];                 // bf16 A path: 64 B per issue
    float4 avP[2][8];                 // fp32 A fallback: 128 B per issue
    short8 wv2[2];                    // W staging regs (32 B)

    auto issueA = [&](int j, int set) {
        const int g = gidx[j];
        if (MODE == 0) {
            #pragma unroll
            for (int u = 0; u < 8; ++u) avP[set][u] = make_float4(0.f,0.f,0.f,0.f);
            if (g >= 0) {
                const float* sp = src_f32 + (size_t)g * 64 + s * 32;
                #pragma unroll
                for (int u = 0; u < 8; ++u)
                    avP[set][u] = *reinterpret_cast<const float4*>(sp + u * 4);
            }
        } else {
            if (g >= 0) {
                const u16* sp = src_b16 + (size_t)g * 64 + s * 32;
                #pragma unroll
                for (int u = 0; u < 4; ++u)
                    avS[set][u] = *reinterpret_cast<const short8*>(sp + u * 8);
            } else {
                #pragma unroll
                for (int u = 0; u < 4; ++u) avS[set][u] = zero8;
            }
        }
    };
    auto writeA = [&](int set, int buf) {
        char* aB = (char*)aL[buf];
        if (MODE == 0) {
            #pragma unroll
            for (int u = 0; u < 8; ++u) {
                us4 t4 = { f2bf(avP[set][u].x), f2bf(avP[set][u].y),
                           f2bf(avP[set][u].z), f2bf(avP[set][u].w) };
                *reinterpret_cast<us4*>(aB + swz(ln, s * 64 + u * 8)) = t4;
            }
        } else {
            #pragma unroll
            for (int u = 0; u < 4; ++u)
                *reinterpret_cast<short8*>(aB + swz(ln, s * 64 + u * 16)) = avS[set][u];
        }
    };
    auto issueW = [&](int j) {
        const u16* src = Wt + (size_t)wrow * 576 + j * 64 + ws4 * 16;
        wv2[0] = *reinterpret_cast<const short8*>(src);
        wv2[1] = *reinterpret_cast<const short8*>(src + 8);
    };
    auto writeW = [&](int buf) {
        char* wB = (char*)wL[buf];
        *reinterpret_cast<short8*>(wB + swz(wrow, ws4 * 32))      = wv2[0];
        *reinterpret_cast<short8*>(wB + swz(wrow, ws4 * 32 + 16)) = wv2[1];
    };
    auto stageWv = [&]() {
        const u16* src = Wvt + (size_t)wrow * 64 + ws4 * 16;
        short8 a = *reinterpret_cast<const short8*>(src);
        short8 b = *reinterpret_cast<const short8*>(src + 8);
        char* wB = (char*)wL[1];
        *reinterpret_cast<short8*>(wB + swz(wrow, ws4 * 32))      = a;
        *reinterpret_cast<short8*>(wB + swz(wrow, ws4 * 32 + 16)) = b;
    };

    // ---- accumulators: bias broadcast; per wave 2 row-frags x 4 col-frags --
    f32x4 acc[2][4];
    #pragma unroll
    for (int ar = 0; ar < 2; ++ar)
        #pragma unroll
        for (int cf = 0; cf < 4; ++cf) {
            float b = bvec[cf * 16 + cq];
            acc[ar][cf] = f32x4{b, b, b, b};
        }

    auto computeChunk = [&](int buf, f32x4 (*ac)[4]) {
        const char* aB = (const char*)aL[buf];
        const char* wB = (const char*)wL[buf];
        #pragma unroll
        for (int ks = 0; ks < 2; ++ks)
            #pragma unroll
            for (int ar = 0; ar < 2; ++ar) {
                short8 afrag = *reinterpret_cast<const short8*>(
                    aB + swz(w * 32 + ar * 16 + cq, ks * 64 + kh * 16));
                #pragma unroll
                for (int cf = 0; cf < 4; ++cf) {
                    short8 bfrag = *reinterpret_cast<const short8*>(
                        wB + swz(cf * 16 + cq, ks * 64 + kh * 16));
                    ac[ar][cf] = __builtin_amdgcn_mfma_f32_16x16x32_bf16(
                        afrag, bfrag, ac[ar][cf], 0, 0, 0);
                }
            }
    };

    // ---- prologue: A(0),A(1) in flight; A(0),W(0) -> LDS ----
    issueA(0, 0); issueA(1, 1); issueW(0);
    writeA(0, 0); writeW(0);
    barrier_no_drain();

    // ---- conv loop (fully unrolled): no-drain barriers, A depth-2 ----
    #pragma unroll
    for (int j = 0; j < 9; ++j) {
        if (j <= 6) issueA(j + 2, j & 1);
        if (j < 8) issueW(j + 1);
        computeChunk(j & 1, acc);
        barrier_no_drain();
        if (j < 8) {
            writeA((j + 1) & 1, (j + 1) & 1);
            writeW((j + 1) & 1);
        } else {
            // final chunk: stage head weights + relu'd hT into free buffers
            stageWv();
            char* hB = (char*)aL[1];
            #pragma unroll
            for (int ar = 0; ar < 2; ++ar)
                #pragma unroll
                for (int cf = 0; cf < 4; ++cf)
                    #pragma unroll
                    for (int r = 0; r < 4; ++r) {
                        float hval = fmaxf(acc[ar][cf][r], 0.f);
                        int row = w * 32 + ar * 16 + kh * 4 + r;  // C/D layout
                        int col = cf * 16 + cq;
                        *reinterpret_cast<u16*>(hB + swz(row, col * 2)) = f2bf(hval);
                    }
        }
        barrier_no_drain();
    }

    // ---- value head: value = relu(h) @ Wv  (aL[1]=hT, wL[1]=Wv) ----
    f32x4 vacc[2][4];
    #pragma unroll
    for (int ar = 0; ar < 2; ++ar)
        #pragma unroll
        for (int cf = 0; cf < 4; ++cf) vacc[ar][cf] = f32x4{0.f, 0.f, 0.f, 0.f};
    computeChunk(1, vacc);

    #pragma unroll
    for (int ar = 0; ar < 2; ++ar)
        #pragma unroll
        for (int cf = 0; cf < 4; ++cf)
            #pragma unroll
            for (int r = 0; r < 4; ++r) {
                int node = base + w * 32 + ar * 16 + kh * 4 + r;
                if (node < N)
                    value_out[(size_t)node * 64 + cf * 16 + cq] = vacc[ar][cf][r];
            }

    // ---- parent: write bf16 h (ungated) to workspace, coalesced ----
    if (MODE == 0 || MODE == 1) {
        int node = base + ln;
        if (node < N) {
            const char* hB = (const char*)aL[1];
            u16* dst = h_out + (size_t)node * 64 + s * 32;
            #pragma unroll
            for (int u = 0; u < 4; ++u) {
                short8 x = *reinterpret_cast<const short8*>(hB + swz(ln, s * 64 + u * 16));
                *reinterpret_cast<short8*>(dst + u * 8) = x;
            }
        }
    }

    // ---- split head: split[n] = dot(h[n], Ws); 2 threads per node ----
    {
        const char* hB = (const char*)aL[1];
        float sp = 0.f;
        #pragma unroll
        for (int u2 = 0; u2 < 4; ++u2) {
            short8 hv = *reinterpret_cast<const short8*>(hB + swz(ln, s * 64 + u2 * 16));
            #pragma unroll
            for (int e = 0; e < 8; ++e)
                sp += bf2f((u16)hv[e]) * Ws[s * 32 + u2 * 8 + e];
        }
        sp += __shfl_xor(sp, 1);
        if (s == 0) {
            int node = base + ln;
            if (node < N) split_out[node] = sp;
        }
    }
}

extern "C" void kernel_launch(void* const* d_in, const int* in_sizes, int n_in,
                              void* d_out, int out_size, void* d_ws, size_t ws_size,
                              hipStream_t stream) {
    const float* feat       = (const float*)d_in[0];
    const int*   neigh_d    = (const int*)d_in[1];
    const int*   neigh_d1   = (const int*)d_in[2];
    const int*   parent_idx = (const int*)d_in[3];
    const float* split_gt   = (const float*)d_in[4];
    const float* W1  = (const float*)d_in[5];
    const float* b1  = (const float*)d_in[6];
    const float* W2  = (const float*)d_in[7];
    const float* b2  = (const float*)d_in[8];
    const float* Ws1 = (const float*)d_in[9];
    const float* Wv1 = (const float*)d_in[10];
    const float* Ws2 = (const float*)d_in[11];
    const float* Wv2 = (const float*)d_in[12];

    float* out    = (float*)d_out;
    float* split1 = out;
    float* value1 = out + NPARENT;
    float* split2 = out + NPARENT + (size_t)NPARENT * 64;
    float* value2 = split2 + NCHILD;

    // ---- workspace layout ----
    u16* h_ws = (u16*)d_ws;                          // [200000][64] bf16, ungated
    u16* Wt1  = h_ws + (size_t)NPARENT * 64;
    u16* Wt2  = Wt1 + 576 * 64;
    u16* Wv1t = Wt2 + 576 * 64;
    u16* Wv2t = Wv1t + 64 * 64;
    u16* endW = Wv2t + 64 * 64;
    size_t offW_bytes = (size_t)(endW - (u16*)d_ws) * 2;

    int*  fused = (int*)((char*)d_ws + offW_bytes);  // [300000][9] int32
    size_t offF_bytes = offW_bytes + (size_t)NCHILD * 9 * 4;
    u16*  featb = (u16*)((char*)d_ws + offF_bytes);  // [200000][64] bf16
    size_t offB_bytes = offF_bytes + (size_t)NPARENT * 64 * 2;

    const bool useFused = ws_size >= offF_bytes;
    const bool useFeatb = ws_size >= offB_bytes;

    const int bW = 145;                              // 145*256 >= 576*64
    const int bF = (NPARENT * 64 / 8 + 255) / 256;   // feat bf16 conversion
    const int bI = (NCHILD * 9 + 255) / 256;         // idx fusion
    prep_all<<<bW + bF + bI, 256, 0, stream>>>(
        W1, W2, Wv1, Wv2, feat, neigh_d1, parent_idx, split_gt,
        Wt1, Wt2, Wv1t, Wv2t, featb, fused,
        bW, bF, useFeatb ? 1 : 0, useFused ? 1 : 0);

    const int gP = (NPARENT + TR - 1) / TR;
    const int gC = (NCHILD + TR - 1) / TR;

    if (useFeatb)
        quad_mfma<1><<<gP, NTHR, 0, stream>>>(
            nullptr, featb, neigh_d, nullptr, nullptr,
            Wt1, b1, Ws1, Wv1t, split1, value1, h_ws, NPARENT);
    else
        quad_mfma<0><<<gP, NTHR, 0, stream>>>(
            feat, nullptr, neigh_d, nullptr, nullptr,
            Wt1, b1, Ws1, Wv1t, split1, value1, h_ws, NPARENT);

    if (useFused)
        quad_mfma<2><<<gC, NTHR, 0, stream>>>(
            nullptr, h_ws, fused, nullptr, nullptr,
            Wt2, b2, Ws2, Wv2t, split2, value2, nullptr, NCHILD);
    else
        quad_mfma<3><<<gC, NTHR, 0, stream>>>(
            nullptr, h_ws, neigh_d1, parent_idx, split_gt,
            Wt2, b2, Ws2, Wv2t, split2, value2, nullptr, NCHILD);
}